// Round 12
// baseline (274.864 us; speedup 1.0000x reference)
//
#include <hip/hip_runtime.h>
#include <hip/hip_bf16.h>
#include <cmath>

#define DIM 512
#define HID 256
#define ROWS_PB 64       // rows per block: 8 waves = 4 tiles x 2 sources
#define NCHUNK 16        // K chunks of 32
#define CB 16384         // B chunk bytes: 32k * 256c * 2B

typedef __attribute__((ext_vector_type(8))) short short8;
typedef __attribute__((ext_vector_type(4))) float f32x4;
typedef __attribute__((ext_vector_type(4))) unsigned int u32x4;

__device__ __forceinline__ unsigned short f2bf(float f) {
  union { float f; unsigned u; } v; v.f = f;
  unsigned u = v.u;
  return (unsigned short)((u + 0x7FFFu + ((u >> 16) & 1u)) >> 16);
}

// Pre-swizzle W1 (fp32 [512,256] row-major) into bf16 MFMA fragment order:
// w1s[((k>>3)*HID + c)*8 + (k&7)]. K-chunk c (32 k's) is the contiguous
// 16 KB at byte offset c*16384 — a linear copy.
__global__ void w1_swz_kernel(const float* __restrict__ W1,
                              unsigned short* __restrict__ w1s) {
  int tid = blockIdx.x * blockDim.x + threadIdx.x;
  if (tid >= DIM * HID) return;
  int k = tid / HID;
  int c = tid - k * HID;
  w1s[(((k >> 3) * HID) + c) * 8 + (k & 7)] = f2bf(W1[tid]);
}

__device__ __forceinline__ short8 cvt8(const f32x4 p0, const f32x4 p1) {
  short8 r;
  r[0] = (short)f2bf(p0[0]); r[1] = (short)f2bf(p0[1]);
  r[2] = (short)f2bf(p0[2]); r[3] = (short)f2bf(p0[3]);
  r[4] = (short)f2bf(p1[0]); r[5] = (short)f2bf(p1[1]);
  r[6] = (short)f2bf(p1[2]); r[7] = (short)f2bf(p1[3]);
  return r;
}

// 8 waves / 64 rows. Wave w: src s=w&1 (z1/z2), row-tile=w>>1, FULL hid.
// A (z) is STREAMED through the K-loop (2-chunk lookahead, 32B/lane/chunk)
// so the block issues HBM reads continuously — the K-loop self-paces at the
// per-CU HBM rate instead of bursting then idling. B staged via T14
// (global->reg early, ds_write late), double-buffered, one barrier/chunk.
__global__ __launch_bounds__(512, 2) void fa_main_kernel(
    const float* __restrict__ z1, const float* __restrict__ z2,
    const unsigned short* __restrict__ w1s,
    const float* __restrict__ bias1, const float* __restrict__ W2,
    const float* __restrict__ bias2, float* __restrict__ out, int n) {
  __shared__ char Bbuf[2][CB];        // 32 KB double buffer
  __shared__ float xs[2][ROWS_PB];    // logits [src][row]

  const int t = threadIdx.x;
  const int w = t >> 6;
  const int l = t & 63;
  const int l15 = l & 15, l16 = l >> 4;
  const int s = w & 1;    // source this wave scores
  const int tile = w >> 1;  // row tile 0..3
  const int row0 = blockIdx.x * ROWS_PB;
  const int myrow = row0 + tile * 16 + l15;
  const bool rok = myrow < n;
  const float* zz = s ? z2 : z1;
  const float* ap = zz + (size_t)myrow * DIM + (l16 << 3);
  const f32x4 zf4 = (f32x4){0.f, 0.f, 0.f, 0.f};

  // T14 B-staging: 2 KB/wave/chunk = 2 x 16 B pieces per lane.
  u32x4 breg0, breg1;
#define BLOAD(c)                                              \
  {                                                           \
    const u32x4* g = (const u32x4*)w1s + (c) * 1024 + l;      \
    breg0 = g[w * 64];                                        \
    breg1 = g[(w + 8) * 64];                                  \
  }
#define BWRITE(c)                                             \
  {                                                           \
    u32x4* d = (u32x4*)&Bbuf[(c) & 1][0] + l;                 \
    d[w * 64] = breg0;                                        \
    d[(w + 8) * 64] = breg1;                                  \
  }

  // Prologue: B[0] via regs; A chunks 0,1 into the 2-deep pipe.
  BLOAD(0);
  f32x4 pa0[2], pa1[2];
  pa0[0] = rok ? *(const f32x4*)(ap) : zf4;
  pa0[1] = rok ? *(const f32x4*)(ap + 4) : zf4;
  pa1[0] = rok ? *(const f32x4*)(ap + 32) : zf4;
  pa1[1] = rok ? *(const f32x4*)(ap + 36) : zf4;
  BWRITE(0);

  f32x4 acc[16];
#pragma unroll
  for (int f = 0; f < 16; ++f) acc[f] = zf4;

  __syncthreads();  // B[0] + A[0],A[1] resident

  // K-loop: chunk c computes with A[c] (pa slot c&1) and Bbuf[c&1];
  // issues B[c+1] (L2) and A[c+2] (HBM) early, writes B[c+1] late.
#pragma unroll
  for (int c = 0; c < NCHUNK; ++c) {
    const short8 af =
        (c & 1) ? cvt8(pa1[0], pa1[1]) : cvt8(pa0[0], pa0[1]);
    if (c + 1 < NCHUNK) BLOAD(c + 1);
    if (c + 2 < NCHUNK) {
      const float* apn = ap + ((c + 2) << 5);
      if (c & 1) {
        pa1[0] = rok ? *(const f32x4*)(apn) : zf4;
        pa1[1] = rok ? *(const f32x4*)(apn + 4) : zf4;
      } else {
        pa0[0] = rok ? *(const f32x4*)(apn) : zf4;
        pa0[1] = rok ? *(const f32x4*)(apn + 4) : zf4;
      }
    }
    __builtin_amdgcn_sched_barrier(0);  // pin early issue of B/A loads
    const short8* bp =
        (const short8*)&Bbuf[c & 1][0] + (l16 << 8) + l15;
#pragma unroll
    for (int f = 0; f < 16; ++f) {
      const short8 bf = bp[f << 4];
      acc[f] =
          __builtin_amdgcn_mfma_f32_16x16x32_bf16(af, bf, acc[f], 0, 0, 0);
    }
    if (c + 1 < NCHUNK) BWRITE(c + 1);  // waits breg only (A stays in flight)
    __syncthreads();
  }

  // Logits: full hid per wave. C/D: col = f*16+l15, row-in-tile = l16*4+r.
  float part[4] = {0.f, 0.f, 0.f, 0.f};
#pragma unroll
  for (int f = 0; f < 16; ++f) {
    const int cc = (f << 4) + l15;
    const float w2v = W2[cc];
    const float b1v = bias1[cc];
#pragma unroll
    for (int r = 0; r < 4; ++r) {
      const float hh = acc[f][r] + b1v;
      part[r] += (hh > 0.f) ? hh * w2v : 0.f;
    }
  }
#pragma unroll
  for (int r = 0; r < 4; ++r) {
#pragma unroll
    for (int m = 1; m < 16; m <<= 1) part[r] += __shfl_xor(part[r], m, 16);
  }
  if (l15 == 0) {
#pragma unroll
    for (int r = 0; r < 4; ++r)
      xs[s][tile * 16 + (l16 << 2) + r] = part[r];
  }
  __syncthreads();

  // Epilogue: wave (tile,s) covers its 16 rows, column half s*256..+256.
  // Re-reads are L2/L3-hot (rows fetched by this block moments ago).
  const int colh = s << 8;
#pragma unroll 2
  for (int r = 0; r < 16; ++r) {
    const int rl = tile * 16 + r;
    const int grow = row0 + rl;
    if (grow < n) {
      const float x = xs[0][rl];
      const float y = xs[1][rl];
      const float sx = 1.f / (1.f + __expf(y - x));  // b2 cancels
      const float sy = 1.f - sx;
      const size_t off = (size_t)grow * DIM + colh + (l << 2);
      const f32x4 a4 = *(const f32x4*)(z1 + off);
      const f32x4 b4 = *(const f32x4*)(z2 + off);
      f32x4 o;
      o[0] = sx * a4[0] + sy * b4[0];
      o[1] = sx * a4[1] + sy * b4[1];
      o[2] = sx * a4[2] + sy * b4[2];
      o[3] = sx * a4[3] + sy * b4[3];
      *(f32x4*)(out + off) = o;
    }
  }
#undef BLOAD
#undef BWRITE
}

extern "C" void kernel_launch(void* const* d_in, const int* in_sizes, int n_in,
                              void* d_out, int out_size, void* d_ws,
                              size_t ws_size, hipStream_t stream) {
  const float* z1 = (const float*)d_in[0];
  const float* z2 = (const float*)d_in[1];
  const float* W1 = (const float*)d_in[2];
  const float* b1 = (const float*)d_in[3];
  const float* W2 = (const float*)d_in[4];
  const float* b2 = (const float*)d_in[5];
  float* out = (float*)d_out;
  const int n = in_sizes[0] / DIM;
  unsigned short* w1s = (unsigned short*)d_ws;  // 512*256*2 = 256 KB

  hipLaunchKernelGGL(w1_swz_kernel, dim3((DIM * HID + 255) / 256), dim3(256),
                     0, stream, W1, w1s);
  const int nwg = (n + ROWS_PB - 1) / ROWS_PB;
  hipLaunchKernelGGL(fa_main_kernel, dim3(nwg), dim3(512), 0, stream, z1, z2,
                     w1s, b1, W2, b2, out, n);
}

// Round 13
// 187.202 us; speedup vs baseline: 1.4683x; 1.4683x over previous
//
#include <hip/hip_runtime.h>
#include <hip/hip_bf16.h>
#include <cmath>

#define DIM 512
#define HID 256
#define ROWS_PB 32       // rows per block (100000 = 3125 * 32, no tail)
#define NCHUNK 16        // K chunks of 32
#define CB 16384         // B chunk bytes: 32k * 256c * 2B

typedef __attribute__((ext_vector_type(8))) short short8;
typedef __attribute__((ext_vector_type(4))) float f32x4;
typedef __attribute__((ext_vector_type(4))) unsigned int u32x4;

__device__ __forceinline__ unsigned short f2bf(float f) {
  union { float f; unsigned u; } v; v.f = f;
  unsigned u = v.u;
  return (unsigned short)((u + 0x7FFFu + ((u >> 16) & 1u)) >> 16);
}
__device__ __forceinline__ float bf2f(short h) {
  union { unsigned u; float f; } v;
  v.u = ((unsigned)(unsigned short)h) << 16;
  return v.f;
}

// Pre-swizzle W1 (fp32 [512,256] row-major) into bf16 MFMA fragment order:
// w1s[((k>>3)*HID + c)*8 + (k&7)]. K-chunk c (32 k's) is the contiguous
// 16 KB at byte offset c*16384 — a linear copy.
__global__ void w1_swz_kernel(const float* __restrict__ W1,
                              unsigned short* __restrict__ w1s) {
  int tid = blockIdx.x * blockDim.x + threadIdx.x;
  if (tid >= DIM * HID) return;
  int k = tid / HID;
  int c = tid - k * HID;
  w1s[(((k >> 3) * HID) + c) * 8 + (k & 7)] = f2bf(W1[tid]);
}

__device__ __forceinline__ short8 cvt8(const f32x4 p0, const f32x4 p1) {
  short8 r;
  r[0] = (short)f2bf(p0[0]); r[1] = (short)f2bf(p0[1]);
  r[2] = (short)f2bf(p0[2]); r[3] = (short)f2bf(p0[3]);
  r[4] = (short)f2bf(p1[0]); r[5] = (short)f2bf(p1[1]);
  r[6] = (short)f2bf(p1[2]); r[7] = (short)f2bf(p1[3]);
  return r;
}

__device__ __forceinline__ void wcombine(float wa, const short8 a, float wb,
                                         const short8 b, f32x4& o0, f32x4& o1) {
#pragma unroll
  for (int i = 0; i < 4; ++i) {
    o0[i] = wa * bf2f(a[i]) + wb * bf2f(b[i]);
    o1[i] = wa * bf2f(a[i + 4]) + wb * bf2f(b[i + 4]);
  }
}

// 4 waves / 32 rows. Wave (s = w&1: source, t = w>>1: 16-row tile); each
// wave computes FULL hid for its 16 rows of its source.
// Phase 1: pure HBM burst -> Az (64 KB, bf16 fragments, z read ONCE).
// Phase 2: L2-only K-loop, single-buffered B (16 KB) via T14 reg-staging;
//          per chunk ALL 17 fragment ds_reads batched (sched_barrier-fenced)
//          before the 16-MFMA cluster -> one lgkm wait, not 9 serial chains.
// Phase 3: full logits per wave; epilogue entirely from Az.
// LDS 80 KB -> 2 blocks/CU: one block's HBM phases overlap the other's
// L2-only K-loop.
__global__ __launch_bounds__(256, 2) void fa_main_kernel(
    const float* __restrict__ z1, const float* __restrict__ z2,
    const unsigned short* __restrict__ w1s,
    const float* __restrict__ bias1, const float* __restrict__ W2,
    const float* __restrict__ bias2, float* __restrict__ out, int n) {
  // Az [src][chunk][tile][lane] short8 = 64 KB; Bs 16 KB (xs aliases Bs
  // after the K-loop). Total 80 KB static.
  __shared__ char smem[81920];
  short8* Az = (short8*)smem;
  char* Bs = smem + 65536;
  float* xs = (float*)(smem + 65536);  // [src][32 rows], used post-K-loop

  const int t = threadIdx.x;
  const int w = t >> 6;
  const int l = t & 63;
  const int l15 = l & 15, l16 = l >> 4;
  const int s = w & 1;    // source
  const int tl = w >> 1;  // row tile 0..1
  const int row0 = blockIdx.x * ROWS_PB;
  const int myrow = row0 + tl * 16 + l15;
  const bool rok = myrow < n;
  const float* zz = s ? z2 : z1;
  const float* ap = zz + (size_t)myrow * DIM + (l16 << 3);
  const f32x4 zf4 = (f32x4){0.f, 0.f, 0.f, 0.f};

  // T14 B-staging: 16 KB/chunk = 4 x u32x4 per thread.
  u32x4 breg0, breg1, breg2, breg3;
#define BLOAD(c)                                            \
  {                                                         \
    const u32x4* g = (const u32x4*)w1s + (c) * 1024 + t;    \
    breg0 = g[0];                                           \
    breg1 = g[256];                                         \
    breg2 = g[512];                                         \
    breg3 = g[768];                                         \
  }
#define BWRITE()                                            \
  {                                                         \
    u32x4* d = (u32x4*)Bs + t;                              \
    d[0] = breg0;                                           \
    d[256] = breg1;                                         \
    d[512] = breg2;                                         \
    d[768] = breg3;                                         \
  }

  // ---- Phase 1: B[0] issue, then the A burst (4 groups x 8 indep loads).
  BLOAD(0);
  __builtin_amdgcn_sched_barrier(0);
#pragma unroll
  for (int g = 0; g < 4; ++g) {
    f32x4 p[4][2];
#pragma unroll
    for (int j = 0; j < 4; ++j) {
      const float* pp = ap + (((g << 2) + j) << 5);
      p[j][0] = rok ? *(const f32x4*)(pp) : zf4;
      p[j][1] = rok ? *(const f32x4*)(pp + 4) : zf4;
    }
#pragma unroll
    for (int j = 0; j < 4; ++j)
      Az[((s * NCHUNK + (g << 2) + j) * 2 + tl) * 64 + l] =
          cvt8(p[j][0], p[j][1]);
  }
  BWRITE();  // waits only breg (landed long ago, L2)
  __syncthreads();  // Az + B[0] visible

  f32x4 acc[16];
#pragma unroll
  for (int f = 0; f < 16; ++f) acc[f] = zf4;

  // ---- Phase 2: K-loop, L2-only. Single-buffered B, 2 barriers/chunk.
#pragma unroll
  for (int c = 0; c < NCHUNK; ++c) {
    if (c + 1 < NCHUNK) BLOAD(c + 1);  // early issue (L2), consumed post-MFMA
    __builtin_amdgcn_sched_barrier(0);
    // Batched fragment reads: af + 16 B-frags, all in flight together.
    const short8* bp = (const short8*)Bs + (l16 << 8) + l15;
    const short8 af = Az[((s * NCHUNK + c) * 2 + tl) * 64 + l];
    short8 bf[16];
#pragma unroll
    for (int f = 0; f < 16; ++f) bf[f] = bp[f << 4];
    __builtin_amdgcn_sched_barrier(0);  // reads above, MFMAs below
#pragma unroll
    for (int f = 0; f < 16; ++f)
      acc[f] =
          __builtin_amdgcn_mfma_f32_16x16x32_bf16(af, bf[f], acc[f], 0, 0, 0);
    __syncthreads();  // all reads of Bs done; BLOAD already landed
    if (c + 1 < NCHUNK) BWRITE();
    __syncthreads();  // new B chunk visible
  }

  // ---- Phase 3a: full logit per wave. C/D: col = f*16+l15, row = l16*4+r.
  float part[4] = {0.f, 0.f, 0.f, 0.f};
#pragma unroll
  for (int f = 0; f < 16; ++f) {
    const int cc = (f << 4) + l15;
    const float w2v = W2[cc];
    const float b1v = bias1[cc];
#pragma unroll
    for (int r = 0; r < 4; ++r) {
      const float hh = acc[f][r] + b1v;
      part[r] += (hh > 0.f) ? hh * w2v : 0.f;
    }
  }
#pragma unroll
  for (int r = 0; r < 4; ++r) {
#pragma unroll
    for (int m = 1; m < 16; m <<= 1) part[r] += __shfl_xor(part[r], m, 16);
  }
  if (l15 == 0) {
#pragma unroll
    for (int r = 0; r < 4; ++r)
      xs[s * ROWS_PB + tl * 16 + (l16 << 2) + r] = part[r];
  }
  __syncthreads();

  // ---- Phase 3b: scores + output, entirely from Az (no HBM reads).
  const float x = xs[tl * 16 + l15];
  const float y = xs[ROWS_PB + tl * 16 + l15];
  const float sx = 1.f / (1.f + __expf(y - x));  // b2 cancels
  const float sy = 1.f - sx;
  float* orow = out + (size_t)myrow * DIM + (l16 << 3);
  if (rok) {
#pragma unroll
    for (int j = 0; j < 8; ++j) {
      const int cc = (s << 3) + j;  // this wave covers column chunks s*8..+8
      const short8 a0 = Az[((0 * NCHUNK + cc) * 2 + tl) * 64 + l];
      const short8 a1 = Az[((1 * NCHUNK + cc) * 2 + tl) * 64 + l];
      f32x4 o0, o1;
      wcombine(sx, a0, sy, a1, o0, o1);
      *(f32x4*)(orow + (cc << 5)) = o0;
      *(f32x4*)(orow + (cc << 5) + 4) = o1;
    }
  }
#undef BLOAD
#undef BWRITE
}

extern "C" void kernel_launch(void* const* d_in, const int* in_sizes, int n_in,
                              void* d_out, int out_size, void* d_ws,
                              size_t ws_size, hipStream_t stream) {
  const float* z1 = (const float*)d_in[0];
  const float* z2 = (const float*)d_in[1];
  const float* W1 = (const float*)d_in[2];
  const float* b1 = (const float*)d_in[3];
  const float* W2 = (const float*)d_in[4];
  const float* b2 = (const float*)d_in[5];
  float* out = (float*)d_out;
  const int n = in_sizes[0] / DIM;
  unsigned short* w1s = (unsigned short*)d_ws;  // 512*256*2 = 256 KB

  hipLaunchKernelGGL(w1_swz_kernel, dim3((DIM * HID + 255) / 256), dim3(256),
                     0, stream, W1, w1s);
  const int nwg = (n + ROWS_PB - 1) / ROWS_PB;
  hipLaunchKernelGGL(fa_main_kernel, dim3(nwg), dim3(256), 0, stream, z1, z2,
                     w1s, b1, W2, b2, out, n);
}